// Round 1
// baseline (973.202 us; speedup 1.0000x reference)
//
#include <hip/hip_runtime.h>

namespace {

constexpr int KK   = 7;
constexpr int PADC = 3;
constexpr int B = 8, C = 64, T = 32, H = 56, W = 56;

constexpr int ROWS = 8;                      // output rows per block
constexpr int NTHR = 448;                    // 7 dy * 8 chunks * 8 rows
constexpr int NBLK = B * T * (H / ROWS);     // 1792

// LDS layout (floats)
constexpr int X2_STRIDE = 132;               // 8 chunks*16 + 4 pad (132 % 32 == 4)
constexpr int X2_ROWS   = ROWS + KK - 1;     // 14
constexpr int X2_SIZE   = X2_ROWS * X2_STRIDE;   // 1848
constexpr int X1_STRIDE = 68;                // 8 chunks*8 + 4 pad
constexpr int X1_SIZE   = ROWS * X1_STRIDE;  // 544
constexpr int W_SIZE    = C * 56;            // [c][dy*8+j], 3584
constexpr int BUF_SIZE  = X2_SIZE + X1_SIZE; // 2392
constexpr int SMEM_FLOATS = W_SIZE + 2 * BUF_SIZE;  // 8368 floats = 33.5 KB

__global__ __launch_bounds__(NTHR)
void corr_fwd(const float* __restrict__ x, const float* __restrict__ fw,
              float* __restrict__ out) {
  __shared__ float smem[SMEM_FLOATS];
  float* w_s = smem;

  const int tid = threadIdx.x;
  const int dy  = tid % 7;
  const int q   = (tid / 7) % 8;
  const int r   = tid / 56;

  int blk = blockIdx.x;
  const int rt = blk % (H / ROWS);
  blk /= (H / ROWS);
  const int t = blk % T;
  const int b = blk / T;
  const int h0 = rt * ROWS;
  const int tp = (t > 0) ? (t - 1) : 0;

  // ---- stage weights * (1/64) for all c, padded to 8 per (c,dy) row ----
  for (int sid = tid; sid < W_SIZE; sid += NTHR) {
    const int c   = sid / 56;
    const int rm  = sid - c * 56;
    const int dyw = rm >> 3;
    const int j   = rm & 7;
    float v = 0.f;
    if (j < 7) v = fw[((c * T + t) * KK + dyw) * KK + j] * (1.0f / 64.0f);
    w_s[sid] = v;
  }

  // ---- precompute staging coordinates (hoisted out of c loop) ----
  // x2 tile: 14 rows x 8 chunks x 16 floats = 1792 slots = 4 per thread
  int   g2[4]; float m2[4]; int l2[4];
#pragma unroll
  for (int k = 0; k < 4; ++k) {
    const int sid = tid + k * NTHR;
    const int rr  = sid >> 7;          // /128
    const int qq  = (sid >> 4) & 7;
    const int j   = sid & 15;
    const int hg  = h0 + rr - PADC;
    const int wg  = qq * 7 + j - PADC;
    const bool ok = (hg >= 0) && (hg < H) && (wg >= 0) && (wg < W);
    g2[k] = ok ? (hg * W + wg) : 0;
    m2[k] = ok ? 1.f : 0.f;
    l2[k] = rr * X2_STRIDE + qq * 16 + j;
  }
  // x1 tile: 8 rows x 8 chunks x 8 floats = 512 slots; slot A all, slot B tid<64
  int g1a, l1a; float m1a;
  {
    const int sid = tid;
    const int rr  = sid >> 6;
    const int qq  = (sid >> 3) & 7;
    const int j   = sid & 7;
    const int wg  = qq * 7 + j;
    const bool ok = (wg < W);
    g1a = ok ? ((h0 + rr) * W + wg) : 0;
    m1a = ok ? 1.f : 0.f;
    l1a = rr * X1_STRIDE + qq * 8 + j;
  }
  const bool hasB = (tid < 512 - NTHR);
  int g1b = 0, l1b = 0; float m1b = 0.f;
  if (hasB) {
    const int sid = tid + NTHR;
    const int rr  = sid >> 6;
    const int qq  = (sid >> 3) & 7;
    const int j   = sid & 7;
    const int wg  = qq * 7 + j;
    const bool ok = (wg < W);
    g1b = ok ? ((h0 + rr) * W + wg) : 0;
    m1b = ok ? 1.f : 0.f;
    l1b = rr * X1_STRIDE + qq * 8 + j;
  }

  float acc[7][7];
#pragma unroll
  for (int a = 0; a < 7; ++a)
#pragma unroll
    for (int e = 0; e < 7; ++e) acc[a][e] = 0.f;

  const size_t slice   = (size_t)H * W;        // 3136
  const size_t cstride = (size_t)T * slice;    // 100352
  const float* xb2 = x + ((size_t)(b * C) * T + t)  * slice;
  const float* xb1 = x + ((size_t)(b * C) * T + tp) * slice;

  for (int c = 0; c < C; ++c) {
    float* bufp = smem + W_SIZE + (c & 1) * BUF_SIZE;
    float* x2s = bufp;
    float* x1s = bufp + X2_SIZE;
    const float* p2 = xb2 + (size_t)c * cstride;
    const float* p1 = xb1 + (size_t)c * cstride;

#pragma unroll
    for (int k = 0; k < 4; ++k) x2s[l2[k]] = p2[g2[k]] * m2[k];
    x1s[l1a] = p1[g1a] * m1a;
    if (hasB) x1s[l1b] = p1[g1b] * m1b;

    __syncthreads();  // double-buffered: single barrier per channel

    const float4* zp = reinterpret_cast<const float4*>(x2s + (r + dy) * X2_STRIDE + q * 16);
    const float4 z0 = zp[0], z1 = zp[1], z2v = zp[2], z3v = zp[3];
    const float4* xp = reinterpret_cast<const float4*>(x1s + r * X1_STRIDE + q * 8);
    const float4 xa = xp[0], xbv = xp[1];
    const float4* wp = reinterpret_cast<const float4*>(w_s + c * 56 + dy * 8);
    const float4 wa = wp[0], wbv = wp[1];

    const float zz[16] = {z0.x, z0.y, z0.z, z0.w,  z1.x, z1.y, z1.z, z1.w,
                          z2v.x, z2v.y, z2v.z, z2v.w,  z3v.x, z3v.y, z3v.z, z3v.w};
    const float xx[7]  = {xa.x, xa.y, xa.z, xa.w,  xbv.x, xbv.y, xbv.z};
    const float wv[7]  = {wa.x, wa.y, wa.z, wa.w,  wbv.x, wbv.y, wbv.z};

#pragma unroll
    for (int i = 0; i < 7; ++i) {
#pragma unroll
      for (int dx = 0; dx < 7; ++dx) {
        acc[dx][i] = fmaf(wv[dx], xx[i] * zz[i + dx], acc[dx][i]);
      }
    }
  }

  // ---- coalesced write-out via LDS transpose (7 phases, one per dy) ----
  float* obuf = smem;  // alias weight region (3584 >= 3136 floats)
#pragma unroll 1
  for (int ph = 0; ph < 7; ++ph) {
    __syncthreads();
    if (dy == ph) {
#pragma unroll
      for (int dx = 0; dx < 7; ++dx)
#pragma unroll
        for (int i = 0; i < 7; ++i)
          obuf[(dx * ROWS + r) * W + q * 7 + i] = acc[dx][i];
    }
    __syncthreads();
#pragma unroll
    for (int mi = 0; mi < 7; ++mi) {
      const int m   = tid + mi * NTHR;
      const int dxl = m / (ROWS * W);
      const int pos = m - dxl * (ROWS * W);
      const int ch  = ph * 7 + dxl;
      out[((size_t)(b * 49 + ch) * T + t) * slice + (size_t)h0 * W + pos] = obuf[m];
    }
  }
}

}  // namespace

extern "C" void kernel_launch(void* const* d_in, const int* in_sizes, int n_in,
                              void* d_out, int out_size, void* d_ws, size_t ws_size,
                              hipStream_t stream) {
  const float* x  = (const float*)d_in[0];
  const float* fw = (const float*)d_in[1];
  float* out      = (float*)d_out;
  corr_fwd<<<NBLK, NTHR, 0, stream>>>(x, fw, out);
}

// Round 2
// 314.349 us; speedup vs baseline: 3.0959x; 3.0959x over previous
//
#include <hip/hip_runtime.h>

namespace {

constexpr int KK   = 7;
constexpr int PADC = 3;
constexpr int B = 8, C = 64, T = 32, H = 56, W = 56;

constexpr int ROWS = 8;                      // output rows per block
constexpr int NTHR = 448;                    // 7 dy * 8 chunks * 8 rows
constexpr int NBLK = B * T * (H / ROWS);     // 1792

// LDS layout (floats)
constexpr int X2_STRIDE = 132;               // 8 chunks*16 + 4 pad (132 % 32 == 4)
constexpr int X2_ROWS   = ROWS + KK - 1;     // 14
constexpr int X2_SIZE   = X2_ROWS * X2_STRIDE;   // 1848
constexpr int X1_STRIDE = 68;                // 8 chunks*8 + 4 pad
constexpr int X1_SIZE   = ROWS * X1_STRIDE;  // 544
constexpr int CBUF      = X2_SIZE + X1_SIZE; // 2392 floats per channel
constexpr int W_SIZE    = C * 56;            // [c][dy*8+j], 3584
// 2-channel stage, double buffered: 4 channel-buffers + weights
constexpr int SMEM_FLOATS = W_SIZE + 4 * CBUF;   // 13152 floats = 52.6 KB

__global__ __launch_bounds__(NTHR)
void corr_fwd(const float* __restrict__ x, const float* __restrict__ fw,
              float* __restrict__ out) {
  __shared__ float smem[SMEM_FLOATS];
  float* w_s = smem;

  const int tid = threadIdx.x;
  const int dy  = tid % 7;
  const int q   = (tid / 7) % 8;
  const int r   = tid / 56;

  int blk = blockIdx.x;
  const int rt = blk % (H / ROWS);
  blk /= (H / ROWS);
  const int t = blk % T;
  const int b = blk / T;
  const int h0 = rt * ROWS;
  const int tp = (t > 0) ? (t - 1) : 0;

  // ---- stage weights * (1/64) for all c, padded to 8 per (c,dy) row ----
  for (int sid = tid; sid < W_SIZE; sid += NTHR) {
    const int c   = sid / 56;
    const int rm  = sid - c * 56;
    const int dyw = rm >> 3;
    const int j   = rm & 7;
    float v = 0.f;
    if (j < 7) v = fw[((c * T + t) * KK + dyw) * KK + j] * (1.0f / 64.0f);
    w_s[sid] = v;
  }

  // ---- precompute staging coordinates (hoisted out of c loop) ----
  int   g2[4]; float m2[4]; int l2[4];
#pragma unroll
  for (int k = 0; k < 4; ++k) {
    const int sid = tid + k * NTHR;
    const int rr  = sid >> 7;          // /128
    const int qq  = (sid >> 4) & 7;
    const int j   = sid & 15;
    const int hg  = h0 + rr - PADC;
    const int wg  = qq * 7 + j - PADC;
    const bool ok = (hg >= 0) && (hg < H) && (wg >= 0) && (wg < W);
    g2[k] = ok ? (hg * W + wg) : 0;
    m2[k] = ok ? 1.f : 0.f;
    l2[k] = rr * X2_STRIDE + qq * 16 + j;
  }
  int g1a, l1a; float m1a;
  {
    const int sid = tid;
    const int rr  = sid >> 6;
    const int qq  = (sid >> 3) & 7;
    const int j   = sid & 7;
    const int wg  = qq * 7 + j;
    const bool ok = (wg < W);
    g1a = ok ? ((h0 + rr) * W + wg) : 0;
    m1a = ok ? 1.f : 0.f;
    l1a = rr * X1_STRIDE + qq * 8 + j;
  }
  const bool hasB = (tid < 512 - NTHR);
  int g1b = 0, l1b = 0; float m1b = 0.f;
  if (hasB) {
    const int sid = tid + NTHR;
    const int rr  = sid >> 6;
    const int qq  = (sid >> 3) & 7;
    const int j   = sid & 7;
    const int wg  = qq * 7 + j;
    const bool ok = (wg < W);
    g1b = ok ? ((h0 + rr) * W + wg) : 0;
    m1b = ok ? 1.f : 0.f;
    l1b = rr * X1_STRIDE + qq * 8 + j;
  }

  float acc[7][7];
#pragma unroll
  for (int a = 0; a < 7; ++a)
#pragma unroll
    for (int e = 0; e < 7; ++e) acc[a][e] = 0.f;

  const size_t slice   = (size_t)H * W;        // 3136
  const size_t cstride = (size_t)T * slice;    // 100352
  const float* xb2 = x + ((size_t)(b * C) * T + t)  * slice;
  const float* xb1 = x + ((size_t)(b * C) * T + tp) * slice;

  // ---- pipelined staging helpers (2 channels per set) ----
  auto load2 = [&](float (&V2)[2][4], float (&V1a)[2], float (&V1b)[2],
                   const float* b2, const float* b1) {
#pragma unroll
    for (int u = 0; u < 2; ++u) {
      const float* p2 = b2 + (size_t)u * cstride;
      const float* p1 = b1 + (size_t)u * cstride;
#pragma unroll
      for (int k = 0; k < 4; ++k) V2[u][k] = p2[g2[k]];
      V1a[u] = p1[g1a];
      V1b[u] = hasB ? p1[g1b] : 0.f;
    }
  };
  auto write2 = [&](const float (&V2)[2][4], const float (&V1a)[2],
                    const float (&V1b)[2], float* base) {
#pragma unroll
    for (int u = 0; u < 2; ++u) {
      float* x2s = base + u * CBUF;
      float* x1s = x2s + X2_SIZE;
#pragma unroll
      for (int k = 0; k < 4; ++k) x2s[l2[k]] = V2[u][k] * m2[k];
      x1s[l1a] = V1a[u] * m1a;
      if (hasB) x1s[l1b] = V1b[u] * m1b;
    }
  };
  auto compute2 = [&](const float* base, int c0) {
#pragma unroll
    for (int u = 0; u < 2; ++u) {
      const float* x2s = base + u * CBUF;
      const float* x1s = x2s + X2_SIZE;
      const float4* zp = reinterpret_cast<const float4*>(x2s + (r + dy) * X2_STRIDE + q * 16);
      const float4 z0 = zp[0], z1 = zp[1], z2v = zp[2], z3v = zp[3];
      const float4* xp = reinterpret_cast<const float4*>(x1s + r * X1_STRIDE + q * 8);
      const float4 xa = xp[0], xbv = xp[1];
      const float4* wp = reinterpret_cast<const float4*>(w_s + (c0 + u) * 56 + dy * 8);
      const float4 wa = wp[0], wbv = wp[1];

      const float zz[16] = {z0.x, z0.y, z0.z, z0.w,  z1.x, z1.y, z1.z, z1.w,
                            z2v.x, z2v.y, z2v.z, z2v.w,  z3v.x, z3v.y, z3v.z, z3v.w};
      const float xx[7]  = {xa.x, xa.y, xa.z, xa.w,  xbv.x, xbv.y, xbv.z};
      const float wv[7]  = {wa.x, wa.y, wa.z, wa.w,  wbv.x, wbv.y, wbv.z};

#pragma unroll
      for (int i = 0; i < 7; ++i)
#pragma unroll
        for (int dx = 0; dx < 7; ++dx)
          acc[dx][i] = fmaf(wv[dx], xx[i] * zz[i + dx], acc[dx][i]);
    }
  };

  float A2[2][4], A1a[2], A1b[2];
  float Bv2[2][4], B1a[2], B1b[2];

  // prologue: channels 0,1 -> A
  load2(A2, A1a, A1b, xb2, xb1);
  const float* n2 = xb2 + 2 * cstride;
  const float* n1 = xb1 + 2 * cstride;

  float* buf0 = smem + W_SIZE;
  float* buf1 = buf0 + 2 * CBUF;

  for (int s = 0; s < 32; s += 2) {
    // stage s: consume A (ch 2s,2s+1) via buf0; prefetch B (ch 2s+2,2s+3)
    write2(A2, A1a, A1b, buf0);
    load2(Bv2, B1a, B1b, n2, n1);      // 2s+2 <= 62, always valid
    n2 += 2 * cstride; n1 += 2 * cstride;
    __syncthreads();
    compute2(buf0, 2 * s);

    // stage s+1: consume B via buf1; prefetch A (ch 2s+4,2s+5) if any
    write2(Bv2, B1a, B1b, buf1);
    if (s + 2 < 32) {
      load2(A2, A1a, A1b, n2, n1);
      n2 += 2 * cstride; n1 += 2 * cstride;
    }
    __syncthreads();
    compute2(buf1, 2 * s + 2);
  }

  // ---- coalesced write-out via LDS transpose (7 phases, one per dy) ----
  float* obuf = smem;  // alias weight region (3584 >= 3136 floats)
#pragma unroll 1
  for (int ph = 0; ph < 7; ++ph) {
    __syncthreads();
    if (dy == ph) {
#pragma unroll
      for (int dx = 0; dx < 7; ++dx)
#pragma unroll
        for (int i = 0; i < 7; ++i)
          obuf[(dx * ROWS + r) * W + q * 7 + i] = acc[dx][i];
    }
    __syncthreads();
#pragma unroll
    for (int mi = 0; mi < 7; ++mi) {
      const int m   = tid + mi * NTHR;
      const int dxl = m / (ROWS * W);
      const int pos = m - dxl * (ROWS * W);
      const int ch  = ph * 7 + dxl;
      out[((size_t)(b * 49 + ch) * T + t) * slice + (size_t)h0 * W + pos] = obuf[m];
    }
  }
}

}  // namespace

extern "C" void kernel_launch(void* const* d_in, const int* in_sizes, int n_in,
                              void* d_out, int out_size, void* d_ws, size_t ws_size,
                              hipStream_t stream) {
  const float* x  = (const float*)d_in[0];
  const float* fw = (const float*)d_in[1];
  float* out      = (float*)d_out;
  corr_fwd<<<NBLK, NTHR, 0, stream>>>(x, fw, out);
}